// Round 8
// baseline (1839.585 us; speedup 1.0000x reference)
//
#include <hip/hip_runtime.h>
#include <stdint.h>

#define N_ROWS 262144
#define D_DIM  1024
#define H_DIM  512
#define N_SEG  512

typedef __attribute__((ext_vector_type(4)))  float  f32x4;
typedef __attribute__((ext_vector_type(8)))  __bf16 bf16x8;
typedef __attribute__((ext_vector_type(8)))  unsigned short u16x8;

static __device__ __forceinline__ unsigned short c2bf(float f) {
  union { __bf16 b; unsigned short u; } c; c.b = (__bf16)f; return c.u;   // RNE, pairs fuse to cvt_pk
}
static __device__ __forceinline__ float fast_tanh(float u) {
  return 1.0f - 2.0f / (__expf(2.0f * u) + 1.0f);
}

// ---------------- kernel 0: W1,W2 f32 -> bf16 LDS-image layout -------------
// Image for (hs, kt): 16 KB = 16 subtiles (cfi) of 1 KB; subtile = lane l slot
// of 16 B: col c = cfi*16 + (l&15)  [c in [0,256): mat = c>>7, hl = c&127],
// k = kt*32 + (l>>4)*8 + e.  elem idx = (hs*32+kt)*8192 + cfi*512 + l*8 + e.
__global__ void cvt_w(const float* __restrict__ W1, const float* __restrict__ W2,
                      unsigned short* __restrict__ wbf) {
  int gid = blockIdx.x * 256 + threadIdx.x;      // 131072
  int l   = gid & 63;
  int cfi = (gid >> 6) & 15;
  int kt  = (gid >> 10) & 31;
  int hs  = gid >> 15;
  int c   = (cfi << 4) + (l & 15);
  int h   = (hs << 7) + (c & 127);
  int k0  = (kt << 5) + ((l >> 4) << 3);
  const float* src = ((c >> 7) ? W2 : W1) + h * 1024 + k0;
  f32x4 f0 = *(const f32x4*)src;
  f32x4 f1 = *(const f32x4*)(src + 4);
  u16x8 v;
  v[0]=c2bf(f0[0]); v[1]=c2bf(f0[1]); v[2]=c2bf(f0[2]); v[3]=c2bf(f0[3]);
  v[4]=c2bf(f1[0]); v[5]=c2bf(f1[1]); v[6]=c2bf(f1[2]); v[7]=c2bf(f1[3]);
  *(u16x8*)(wbf + (size_t)gid * 8) = v;
}

// ---------------- kernel 1: partial (m,s,n) per (row, h-slice) -------------
// Block = 256 rows x (128 h x 2 mats); 8 waves = 2rg x 4cg; wave = 128r x 64c
// via mfma 16x16x32, acc f32x4[8][4]. BK=32, 32 phases, 2-phase LDS dbuf.
// B via global_load_lds from prebaked image (frag-linear, conflict-free);
// A reg-staged f32->bf16. Barrier = vmcnt(0)+lgkmcnt(0) (loads issued a full
// compute-phase early).
#define ENDBAR() do { \
  asm volatile("s_waitcnt vmcnt(0) lgkmcnt(0)" ::: "memory"); \
  __builtin_amdgcn_s_barrier(); \
} while (0)

#define STAGEB(KT, BOFF) do { \
  __builtin_amdgcn_global_load_lds( \
    (const __attribute__((address_space(1))) void*)(wsrc + ((uint32_t)(KT) << 13)), \
    (__attribute__((address_space(3))) void*)(lds + (BOFF) + (wid << 11)), 16, 0, 0); \
  __builtin_amdgcn_global_load_lds( \
    (const __attribute__((address_space(1))) void*)(wsrc + ((uint32_t)(KT) << 13) + 512), \
    (__attribute__((address_space(3))) void*)(lds + (BOFF) + (wid << 11) + 1024), 16, 0, 0); \
} while (0)

#define COMPUTE(CB) do { \
  bf16x8 bf_[4], af[8]; \
  _Pragma("unroll") \
  for (int fc = 0; fc < 4; ++fc) \
    bf_[fc] = *(const bf16x8*)(lds + (CB) + 16384 + (((cg << 2) + fc) << 10) + (lane << 4)); \
  _Pragma("unroll") \
  for (int fr = 0; fr < 8; ++fr) \
    af[fr] = *(const bf16x8*)(lds + (CB) + (((rg << 3) + fr) << 10) + (lane << 4)); \
  __builtin_amdgcn_s_setprio(1); \
  _Pragma("unroll") \
  for (int fr = 0; fr < 8; ++fr) \
    _Pragma("unroll") \
    for (int fc = 0; fc < 4; ++fc) \
      acc[fr][fc] = __builtin_amdgcn_mfma_f32_16x16x32_bf16(af[fr], bf_[fc], acc[fr][fc], 0, 0, 0); \
  __builtin_amdgcn_s_setprio(0); \
} while (0)

__launch_bounds__(512, 2)
__global__ void alpha_kernel(const float* __restrict__ x,
                             const unsigned short* __restrict__ wbf,
                             const float* __restrict__ W3,
                             float* __restrict__ pm, float* __restrict__ ps,
                             float* __restrict__ pn)
{
  __shared__ unsigned char lds[65536 + 6144];    // 2 x (16K A + 16K B); epi: gx@0, pbuf@65536
  const int tid  = threadIdx.x;
  const int lane = tid & 63;
  const int wid  = tid >> 6;                     // 0..7
  const int rg   = wid >> 2;                     // 0..1  row half (128 rows)
  const int cg   = wid & 3;                      // 0..3  col quarter (64 vcols)
  const int l15  = lane & 15;
  const int lg   = lane >> 4;                    // 0..3
  const int bid  = blockIdx.x;
  const int rt   = ((bid >> 5) << 3) + (bid & 7);   // rowtile 0..1023 (same XCD for all hs)
  const int hs   = (bid >> 3) & 3;                  // h-slice 0..3
  const int row0 = rt << 8;

  // A staging: thread t -> slots t and t+512 (slot = 16B: rfi=s>>6, l=s&63,
  // row = rfi*16+(l&15), k = kt*32+(l>>4)*8+[0,8))
  const int s0r = ((tid >> 6) << 4) + (tid & 15);
  const int s0k = ((tid >> 4) & 3) << 3;
  const float* xsrc0 = x + (size_t)(row0 + s0r) * 1024 + s0k;
  const float* xsrc1 = xsrc0 + (size_t)128 * 1024;

  // B staging source (per-lane): image elems (hs*32+kt)*8192 + (wid*2+i)*512 + lane*8
  const unsigned short* wsrc = wbf + ((uint32_t)hs << 18) + ((uint32_t)wid << 10) + ((uint32_t)lane << 3);

  f32x4 acc[8][4];
  #pragma unroll
  for (int fr = 0; fr < 8; ++fr)
    #pragma unroll
    for (int fc = 0; fc < 4; ++fc) acc[fr][fc] = (f32x4){0.f, 0.f, 0.f, 0.f};

  // prologue: stage kt=0 into buf0 (A@0, B@16384)
  STAGEB(0, 16384);
  {
    f32x4 a0 = *(const f32x4*)xsrc0, a1 = *(const f32x4*)(xsrc0 + 4);
    f32x4 b0 = *(const f32x4*)xsrc1, b1 = *(const f32x4*)(xsrc1 + 4);
    u16x8 va, vb;
    va[0]=c2bf(a0[0]); va[1]=c2bf(a0[1]); va[2]=c2bf(a0[2]); va[3]=c2bf(a0[3]);
    va[4]=c2bf(a1[0]); va[5]=c2bf(a1[1]); va[6]=c2bf(a1[2]); va[7]=c2bf(a1[3]);
    vb[0]=c2bf(b0[0]); vb[1]=c2bf(b0[1]); vb[2]=c2bf(b0[2]); vb[3]=c2bf(b0[3]);
    vb[4]=c2bf(b1[0]); vb[5]=c2bf(b1[1]); vb[6]=c2bf(b1[2]); vb[7]=c2bf(b1[3]);
    *(u16x8*)(lds + (tid << 4)) = va;
    *(u16x8*)(lds + 8192 + (tid << 4)) = vb;
  }
  ENDBAR();

  #pragma unroll 1
  for (int kt = 0; kt < 32; ++kt) {
    const uint32_t cb = (uint32_t)(kt & 1) << 15;         // current pair base
    const uint32_t nb = cb ^ 32768u;                      // next pair base
    f32x4 a0, a1, b0, b1;
    if (kt < 31) {
      STAGEB(kt + 1, nb + 16384);
      const float* p0 = xsrc0 + ((kt + 1) << 5);
      const float* p1 = xsrc1 + ((kt + 1) << 5);
      a0 = *(const f32x4*)p0; a1 = *(const f32x4*)(p0 + 4);
      b0 = *(const f32x4*)p1; b1 = *(const f32x4*)(p1 + 4);
    }
    COMPUTE(cb);
    if (kt < 31) {
      u16x8 va, vb;
      va[0]=c2bf(a0[0]); va[1]=c2bf(a0[1]); va[2]=c2bf(a0[2]); va[3]=c2bf(a0[3]);
      va[4]=c2bf(a1[0]); va[5]=c2bf(a1[1]); va[6]=c2bf(a1[2]); va[7]=c2bf(a1[3]);
      vb[0]=c2bf(b0[0]); vb[1]=c2bf(b0[1]); vb[2]=c2bf(b0[2]); vb[3]=c2bf(b0[3]);
      vb[4]=c2bf(b1[0]); vb[5]=c2bf(b1[1]); vb[6]=c2bf(b1[2]); vb[7]=c2bf(b1[3]);
      *(u16x8*)(lds + nb + (tid << 4)) = va;
      *(u16x8*)(lds + nb + 8192 + (tid << 4)) = vb;
    }
    ENDBAR();
  }

  // ---- epilogue: u-waves (cg<2) hand tanh(u)*W3 to v-waves (cg>=2) via LDS,
  // v-waves reduce (m,s,n) over their 64 h's per row. C/D map (m89):
  // col = lane&15, row = lg*4 + j; global row = row0 + rg*128 + fr*16 + lg*4 + j.
  float w3v[4];
  if (cg < 2) {
    #pragma unroll
    for (int fc = 0; fc < 4; ++fc)
      w3v[fc] = W3[(hs << 7) + (cg << 6) + (fc << 4) + l15];
  }
  float* pmb = (float*)(lds + 65536);            // [2][256]
  float* psb = pmb + 512;
  float* pnb = psb + 512;

  #pragma unroll 1
  for (int fr = 0; fr < 8; ++fr) {
    __syncthreads();                             // gx reuse guard
    if (cg < 2) {
      const int uw = (rg << 1) + cg;
      #pragma unroll
      for (int fc = 0; fc < 4; ++fc) {
        f32x4 g;
        #pragma unroll
        for (int j = 0; j < 4; ++j) g[j] = fast_tanh(acc[fr][fc][j]) * w3v[fc];
        *(f32x4*)(lds + (uw << 12) + (lane << 6) + (fc << 4)) = g;
      }
    }
    __syncthreads();
    if (cg >= 2) {
      const int uw = (rg << 1) + (cg - 2);
      f32x4 gv[4];
      #pragma unroll
      for (int fc = 0; fc < 4; ++fc)
        gv[fc] = *(const f32x4*)(lds + (uw << 12) + (lane << 6) + (fc << 4));
      f32x4 mj, sj, nj;
      #pragma unroll
      for (int j = 0; j < 4; ++j)
        mj[j] = fmaxf(fmaxf(acc[fr][0][j], acc[fr][1][j]), fmaxf(acc[fr][2][j], acc[fr][3][j]));
      #pragma unroll
      for (int d = 1; d < 16; d <<= 1)
        #pragma unroll
        for (int j = 0; j < 4; ++j) mj[j] = fmaxf(mj[j], __shfl_xor(mj[j], d));
      #pragma unroll
      for (int j = 0; j < 4; ++j) { sj[j] = 0.f; nj[j] = 0.f; }
      #pragma unroll
      for (int fc = 0; fc < 4; ++fc)
        #pragma unroll
        for (int j = 0; j < 4; ++j) {
          float p = __expf(acc[fr][fc][j] - mj[j]);
          sj[j] += p;
          nj[j] += gv[fc][j] * p;
        }
      #pragma unroll
      for (int d = 1; d < 16; d <<= 1)
        #pragma unroll
        for (int j = 0; j < 4; ++j) { sj[j] += __shfl_xor(sj[j], d); nj[j] += __shfl_xor(nj[j], d); }
      if (l15 == 0) {
        const int hh = cg - 2;
        #pragma unroll
        for (int j = 0; j < 4; ++j) {
          int r = (rg << 7) + (fr << 4) + (lg << 2) + j;
          pmb[(hh << 8) + r] = mj[j];
          psb[(hh << 8) + r] = sj[j];
          pnb[(hh << 8) + r] = nj[j];
        }
      }
    }
  }
  __syncthreads();
  if (tid < 256) {
    float m0 = pmb[tid], m1 = pmb[256 + tid];
    float M  = fmaxf(m0, m1);
    float e0 = __expf(m0 - M), e1 = __expf(m1 - M);
    float S  = psb[tid] * e0 + psb[256 + tid] * e1;
    float Nn = pnb[tid] * e0 + pnb[256 + tid] * e1;
    size_t r = (size_t)(row0 + tid);
    pm[r * 4 + hs] = M;
    ps[r * 4 + hs] = S;
    pn[r * 4 + hs] = Nn;
  }
}

// ---------------- kernel 1b: combine h-slice partials -> a[i] --------------
__global__ void combine_a(const float* __restrict__ pm, const float* __restrict__ ps,
                          const float* __restrict__ pn, float* __restrict__ a) {
  size_t r = (size_t)blockIdx.x * 256 + threadIdx.x;
  float M = -3.4e38f;
  #pragma unroll
  for (int s = 0; s < 4; ++s) M = fmaxf(M, pm[r * 4 + s]);
  float S = 0.f, Nn = 0.f;
  #pragma unroll
  for (int s = 0; s < 4; ++s) {
    float e = __expf(pm[r * 4 + s] - M);
    S  += ps[r * 4 + s] * e;
    Nn += pn[r * 4 + s] * e;
  }
  a[r] = Nn / S;
}

// ---------------- kernel 2: segment softmax weights ----------------
static __device__ __forceinline__ int lower_bound(const int* __restrict__ batch, int key) {
  int lo = 0, hi = N_ROWS;
  while (lo < hi) { int mid = (lo + hi) >> 1; if (batch[mid] < key) lo = mid + 1; else hi = mid; }
  return lo;
}

__global__ void seg_kernel(const float* __restrict__ a, const int* __restrict__ batch,
                           float* __restrict__ w) {
  __shared__ float sm[8];
  int b = blockIdx.x;
  int start = lower_bound(batch, b);
  int end   = lower_bound(batch, b + 1);
  int tid = threadIdx.x;

  float m = -3.4e38f;
  for (int i = start + tid; i < end; i += 256) m = fmaxf(m, a[i]);
  for (int d = 1; d < 64; d <<= 1) m = fmaxf(m, __shfl_xor(m, d));
  if ((tid & 63) == 0) sm[tid >> 6] = m;
  __syncthreads();
  m = fmaxf(fmaxf(sm[0], sm[1]), fmaxf(sm[2], sm[3]));

  float s = 0.f;
  for (int i = start + tid; i < end; i += 256) s += __expf(a[i] - m);
  for (int d = 1; d < 64; d <<= 1) s += __shfl_xor(s, d);
  if ((tid & 63) == 0) sm[4 + (tid >> 6)] = s;
  __syncthreads();
  s = sm[4] + sm[5] + sm[6] + sm[7];

  float rinv = 1.0f / s;
  for (int i = start + tid; i < end; i += 256) w[i] = __expf(a[i] - m) * rinv;
}

// ---------------- kernel 3: z[b] = sum_i w_i * x_i ----------------
__global__ void z_kernel(const float* __restrict__ x, const float* __restrict__ w,
                         const int* __restrict__ batch, float* __restrict__ z) {
  int b = blockIdx.x >> 2, part = blockIdx.x & 3;
  int start = lower_bound(batch, b);
  int end   = lower_bound(batch, b + 1);
  int len = end - start;
  int ps = start + ((len * part) >> 2);
  int pe = start + ((len * (part + 1)) >> 2);
  int col = threadIdx.x << 2;

  f32x4 acc = (f32x4){0.f, 0.f, 0.f, 0.f};
  for (int i = ps; i < pe; ++i) {
    f32x4 xv = *(const f32x4*)(x + ((size_t)i << 10) + col);
    float wi = w[i];
    acc += xv * wi;
  }
  float* zp = z + ((size_t)b << 10) + col;
  atomicAdd(zp + 0, acc[0]);
  atomicAdd(zp + 1, acc[1]);
  atomicAdd(zp + 2, acc[2]);
  atomicAdd(zp + 3, acc[3]);
}

// ---------------- launch ----------------
extern "C" void kernel_launch(void* const* d_in, const int* in_sizes, int n_in,
                              void* d_out, int out_size, void* d_ws, size_t ws_size,
                              hipStream_t stream) {
  const float* x     = (const float*)d_in[0];
  const int*   batch = (const int*)d_in[1];
  const float* W1    = (const float*)d_in[2];
  const float* W2    = (const float*)d_in[3];
  const float* W3    = (const float*)d_in[4];
  float* z = (float*)d_out;

  // ws: [0,2M) wbf ; [2M,3M) a ; [3M,4M) w ; [4M,8M) pm ; [8M,12M) ps ; [12M,16M) pn
  unsigned short* wbf = (unsigned short*)d_ws;
  float* a  = (float*)((char*)d_ws + (2u << 20));
  float* w  = (float*)((char*)d_ws + (3u << 20));
  float* pm = (float*)((char*)d_ws + (4u << 20));
  float* ps = (float*)((char*)d_ws + (8u << 20));
  float* pn = (float*)((char*)d_ws + (12u << 20));

  (void)hipMemsetAsync(d_out, 0, (size_t)N_SEG * D_DIM * sizeof(float), stream);

  cvt_w<<<512, 256, 0, stream>>>(W1, W2, wbf);

  alpha_kernel<<<4096, 512, 0, stream>>>(x, wbf, W3, pm, ps, pn);

  combine_a<<<N_ROWS / 256, 256, 0, stream>>>(pm, ps, pn, a);

  seg_kernel<<<N_SEG, 256, 0, stream>>>(a, batch, w);

  z_kernel<<<N_SEG * 4, 256, 0, stream>>>(x, w, batch, z);
}

// Round 9
// 1313.153 us; speedup vs baseline: 1.4009x; 1.4009x over previous
//
#include <hip/hip_runtime.h>
#include <stdint.h>

#define N_ROWS 262144
#define D_DIM  1024
#define H_DIM  512
#define N_SEG  512

typedef __attribute__((ext_vector_type(4)))  float  f32x4;
typedef __attribute__((ext_vector_type(8)))  __bf16 bf16x8;
typedef __attribute__((ext_vector_type(8)))  unsigned short u16x8;

static __device__ __forceinline__ unsigned short c2bf(float f) {
  union { __bf16 b; unsigned short u; } c; c.b = (__bf16)f; return c.u;   // RNE, pairs fuse to cvt_pk
}
static __device__ __forceinline__ float fast_tanh(float u) {
  return 1.0f - 2.0f / (__expf(2.0f * u) + 1.0f);
}

// ---------------- kernel 0: W1,W2 f32 -> bf16 LDS-image, u/v interleaved ----
// Image for (hs, kt): 16 KB = 16 subtiles (cfi) of 1 KB; subtile = lane l slot
// of 16 B: col c = cfi*16 + (l&15); mat = c&1 (0=W1,1=W2), h = hs*128 + (c>>1);
// k = kt*32 + (l>>4)*8 + e.  elem idx = (hs*32+kt)*8192 + cfi*512 + l*8 + e.
__global__ void cvt_w(const float* __restrict__ W1, const float* __restrict__ W2,
                      unsigned short* __restrict__ wbf) {
  int gid = blockIdx.x * 256 + threadIdx.x;      // 131072
  int l   = gid & 63;
  int cfi = (gid >> 6) & 15;
  int kt  = (gid >> 10) & 31;
  int hs  = gid >> 15;
  int c   = (cfi << 4) + (l & 15);
  int h   = (hs << 7) + (c >> 1);
  int k0  = (kt << 5) + ((l >> 4) << 3);
  const float* src = ((c & 1) ? W2 : W1) + h * 1024 + k0;
  f32x4 f0 = *(const f32x4*)src;
  f32x4 f1 = *(const f32x4*)(src + 4);
  u16x8 v;
  v[0]=c2bf(f0[0]); v[1]=c2bf(f0[1]); v[2]=c2bf(f0[2]); v[3]=c2bf(f0[3]);
  v[4]=c2bf(f1[0]); v[5]=c2bf(f1[1]); v[6]=c2bf(f1[2]); v[7]=c2bf(f1[3]);
  *(u16x8*)(wbf + (size_t)gid * 8) = v;
}

// ---------------- kernel 1: partial (m,s,n) per (row, h-slice) -------------
// Block = 256 rows x (128 h x {u,v} interleaved); 8 waves = 2rg x 4cg;
// wave = 128r x 64c via mfma 16x16x32, acc f32x4[8][4] (STATIC indexing only).
// BK=32, 32 phases, 2-deep LDS dbuf; B via global_load_lds from image;
// A reg-staged f32->bf16. Epilogue fully in-register via shfl (u/v adjacent).
#define ENDBAR() do { \
  asm volatile("s_waitcnt vmcnt(0) lgkmcnt(0)" ::: "memory"); \
  __builtin_amdgcn_s_barrier(); \
} while (0)

#define STAGEB(KT, BOFF) do { \
  __builtin_amdgcn_global_load_lds( \
    (const __attribute__((address_space(1))) void*)(wsrc + ((uint32_t)(KT) << 13)), \
    (__attribute__((address_space(3))) void*)(lds + (BOFF) + (wid << 11)), 16, 0, 0); \
  __builtin_amdgcn_global_load_lds( \
    (const __attribute__((address_space(1))) void*)(wsrc + ((uint32_t)(KT) << 13) + 512), \
    (__attribute__((address_space(3))) void*)(lds + (BOFF) + (wid << 11) + 1024), 16, 0, 0); \
} while (0)

#define COMPUTE(CB) do { \
  bf16x8 bf_[4], af[8]; \
  _Pragma("unroll") \
  for (int fc = 0; fc < 4; ++fc) \
    bf_[fc] = *(const bf16x8*)(lds + (CB) + 16384 + (((cg << 2) + fc) << 10) + (lane << 4)); \
  _Pragma("unroll") \
  for (int fr = 0; fr < 8; ++fr) \
    af[fr] = *(const bf16x8*)(lds + (CB) + (((rg << 3) + fr) << 10) + (lane << 4)); \
  __builtin_amdgcn_s_setprio(1); \
  _Pragma("unroll") \
  for (int fr = 0; fr < 8; ++fr) \
    _Pragma("unroll") \
    for (int fc = 0; fc < 4; ++fc) \
      acc[fr][fc] = __builtin_amdgcn_mfma_f32_16x16x32_bf16(af[fr], bf_[fc], acc[fr][fc], 0, 0, 0); \
  __builtin_amdgcn_s_setprio(0); \
} while (0)

__launch_bounds__(512, 2)
__global__ void alpha_kernel(const float* __restrict__ x,
                             const unsigned short* __restrict__ wbf,
                             const float* __restrict__ W3,
                             float* __restrict__ pm, float* __restrict__ ps,
                             float* __restrict__ pn)
{
  __shared__ unsigned char lds[65536 + 12288];   // 2 x (16K A + 16K B) + 12K partials
  const int tid  = threadIdx.x;
  const int lane = tid & 63;
  const int wid  = tid >> 6;                     // 0..7
  const int rg   = wid >> 2;                     // 0..1  row half (128 rows)
  const int cg   = wid & 3;                      // 0..3  col quarter (64 vcols = 32 h)
  const int l15  = lane & 15;
  const int lg   = lane >> 4;                    // 0..3
  const int bid  = blockIdx.x;
  const int rt   = ((bid >> 5) << 3) + (bid & 7);   // rowtile (same XCD for all hs)
  const int hs   = (bid >> 3) & 3;                  // h-slice 0..3
  const int row0 = rt << 8;

  // A staging: thread t -> slots t and t+512; slot s: row = (s>>6)*16 + (s&15),
  // k = kt*32 + ((s>>4)&3)*8 + [0,8)
  const int s0r = ((tid >> 6) << 4) + (tid & 15);
  const int s0k = ((tid >> 4) & 3) << 3;
  const float* xsrc0 = x + (size_t)(row0 + s0r) * 1024 + s0k;
  const float* xsrc1 = xsrc0 + (size_t)128 * 1024;

  // B staging source (per-lane)
  const unsigned short* wsrc = wbf + ((uint32_t)hs << 18) + ((uint32_t)wid << 10) + ((uint32_t)lane << 3);

  f32x4 acc[8][4];
  #pragma unroll
  for (int fr = 0; fr < 8; ++fr)
    #pragma unroll
    for (int fc = 0; fc < 4; ++fc) acc[fr][fc] = (f32x4){0.f, 0.f, 0.f, 0.f};

  // prologue: stage kt=0 into buf0 (A@0, B@16384)
  STAGEB(0, 16384);
  {
    f32x4 a0 = *(const f32x4*)xsrc0, a1 = *(const f32x4*)(xsrc0 + 4);
    f32x4 b0 = *(const f32x4*)xsrc1, b1 = *(const f32x4*)(xsrc1 + 4);
    u16x8 va, vb;
    va[0]=c2bf(a0[0]); va[1]=c2bf(a0[1]); va[2]=c2bf(a0[2]); va[3]=c2bf(a0[3]);
    va[4]=c2bf(a1[0]); va[5]=c2bf(a1[1]); va[6]=c2bf(a1[2]); va[7]=c2bf(a1[3]);
    vb[0]=c2bf(b0[0]); vb[1]=c2bf(b0[1]); vb[2]=c2bf(b0[2]); vb[3]=c2bf(b0[3]);
    vb[4]=c2bf(b1[0]); vb[5]=c2bf(b1[1]); vb[6]=c2bf(b1[2]); vb[7]=c2bf(b1[3]);
    *(u16x8*)(lds + (tid << 4)) = va;
    *(u16x8*)(lds + 8192 + (tid << 4)) = vb;
  }
  ENDBAR();

  #pragma unroll 1
  for (int kt = 0; kt < 32; ++kt) {
    const uint32_t cb = (uint32_t)(kt & 1) << 15;         // current pair base
    const uint32_t nb = cb ^ 32768u;                      // next pair base
    f32x4 a0, a1, b0, b1;
    if (kt < 31) {
      STAGEB(kt + 1, nb + 16384);
      const float* p0 = xsrc0 + ((kt + 1) << 5);
      const float* p1 = xsrc1 + ((kt + 1) << 5);
      a0 = *(const f32x4*)p0; a1 = *(const f32x4*)(p0 + 4);
      b0 = *(const f32x4*)p1; b1 = *(const f32x4*)(p1 + 4);
    }
    COMPUTE(cb);
    if (kt < 31) {
      u16x8 va, vb;
      va[0]=c2bf(a0[0]); va[1]=c2bf(a0[1]); va[2]=c2bf(a0[2]); va[3]=c2bf(a0[3]);
      va[4]=c2bf(a1[0]); va[5]=c2bf(a1[1]); va[6]=c2bf(a1[2]); va[7]=c2bf(a1[3]);
      vb[0]=c2bf(b0[0]); vb[1]=c2bf(b0[1]); vb[2]=c2bf(b0[2]); vb[3]=c2bf(b0[3]);
      vb[4]=c2bf(b1[0]); vb[5]=c2bf(b1[1]); vb[6]=c2bf(b1[2]); vb[7]=c2bf(b1[3]);
      *(u16x8*)(lds + nb + (tid << 4)) = va;
      *(u16x8*)(lds + nb + 8192 + (tid << 4)) = vb;
    }
    ENDBAR();
  }

  // ---- epilogue: fully static, in-register via shfl ----
  // C/D map (m89): col = lane&15, row = lg*4 + j. Lane's col c = cg*64+fc*16+l15;
  // parity(c) = parity(lane): even lane holds u[h], odd lane holds v-logit[h],
  // h = hs*128 + (c>>1), same h in adjacent lanes -> shfl_xor(1) moves the gate.
  float w3v[4];
  #pragma unroll
  for (int fc = 0; fc < 4; ++fc)
    w3v[fc] = W3[(hs << 7) + (((cg << 6) + (fc << 4) + l15) >> 1)];

  float* pmb = (float*)(lds + 65536);            // [4 cg][256 rows]
  float* psb = pmb + 1024;
  float* pnb = psb + 1024;

  #pragma unroll
  for (int fr = 0; fr < 8; ++fr) {
    f32x4 mv, sv, nv;
    #pragma unroll
    for (int j = 0; j < 4; ++j) {
      // gate from even lanes
      float g0 = fast_tanh(acc[fr][0][j]) * w3v[0];
      float g1 = fast_tanh(acc[fr][1][j]) * w3v[1];
      float g2 = fast_tanh(acc[fr][2][j]) * w3v[2];
      float g3 = fast_tanh(acc[fr][3][j]) * w3v[3];
      float gs0 = __shfl_xor(g0, 1);
      float gs1 = __shfl_xor(g1, 1);
      float gs2 = __shfl_xor(g2, 1);
      float gs3 = __shfl_xor(g3, 1);
      // v-logits on odd lanes
      float mj = fmaxf(fmaxf(acc[fr][0][j], acc[fr][1][j]),
                       fmaxf(acc[fr][2][j], acc[fr][3][j]));
      mj = fmaxf(mj, __shfl_xor(mj, 2));
      mj = fmaxf(mj, __shfl_xor(mj, 4));
      mj = fmaxf(mj, __shfl_xor(mj, 8));
      float p0 = __expf(acc[fr][0][j] - mj);
      float p1 = __expf(acc[fr][1][j] - mj);
      float p2 = __expf(acc[fr][2][j] - mj);
      float p3 = __expf(acc[fr][3][j] - mj);
      float sj = p0 + p1 + p2 + p3;
      float nj = gs0 * p0 + gs1 * p1 + gs2 * p2 + gs3 * p3;
      sj += __shfl_xor(sj, 2); nj += __shfl_xor(nj, 2);
      sj += __shfl_xor(sj, 4); nj += __shfl_xor(nj, 4);
      sj += __shfl_xor(sj, 8); nj += __shfl_xor(nj, 8);
      mv[j] = mj; sv[j] = sj; nv[j] = nj;
    }
    if (l15 == 1) {                              // lanes 1,17,33,49 (one per lg)
      int idx = (cg << 8) + (rg << 7) + (fr << 4) + (lg << 2);
      *(f32x4*)&pmb[idx] = mv;
      *(f32x4*)&psb[idx] = sv;
      *(f32x4*)&pnb[idx] = nv;
    }
  }
  __syncthreads();
  if (tid < 256) {
    float m0 = pmb[tid], m1 = pmb[256 + tid], m2 = pmb[512 + tid], m3 = pmb[768 + tid];
    float M = fmaxf(fmaxf(m0, m1), fmaxf(m2, m3));
    float e0 = __expf(m0 - M), e1 = __expf(m1 - M), e2 = __expf(m2 - M), e3 = __expf(m3 - M);
    float S  = psb[tid]*e0 + psb[256+tid]*e1 + psb[512+tid]*e2 + psb[768+tid]*e3;
    float Nn = pnb[tid]*e0 + pnb[256+tid]*e1 + pnb[512+tid]*e2 + pnb[768+tid]*e3;
    size_t r = (size_t)(row0 + tid);
    pm[r * 4 + hs] = M;
    ps[r * 4 + hs] = S;
    pn[r * 4 + hs] = Nn;
  }
}

// ---------------- kernel 1b: combine h-slice partials -> a[i] --------------
__global__ void combine_a(const float* __restrict__ pm, const float* __restrict__ ps,
                          const float* __restrict__ pn, float* __restrict__ a) {
  size_t r = (size_t)blockIdx.x * 256 + threadIdx.x;
  float M = -3.4e38f;
  #pragma unroll
  for (int s = 0; s < 4; ++s) M = fmaxf(M, pm[r * 4 + s]);
  float S = 0.f, Nn = 0.f;
  #pragma unroll
  for (int s = 0; s < 4; ++s) {
    float e = __expf(pm[r * 4 + s] - M);
    S  += ps[r * 4 + s] * e;
    Nn += pn[r * 4 + s] * e;
  }
  a[r] = Nn / S;
}

// ---------------- kernel 2: segment softmax weights ----------------
static __device__ __forceinline__ int lower_bound(const int* __restrict__ batch, int key) {
  int lo = 0, hi = N_ROWS;
  while (lo < hi) { int mid = (lo + hi) >> 1; if (batch[mid] < key) lo = mid + 1; else hi = mid; }
  return lo;
}

__global__ void seg_kernel(const float* __restrict__ a, const int* __restrict__ batch,
                           float* __restrict__ w) {
  __shared__ float sm[8];
  int b = blockIdx.x;
  int start = lower_bound(batch, b);
  int end   = lower_bound(batch, b + 1);
  int tid = threadIdx.x;

  float m = -3.4e38f;
  for (int i = start + tid; i < end; i += 256) m = fmaxf(m, a[i]);
  for (int d = 1; d < 64; d <<= 1) m = fmaxf(m, __shfl_xor(m, d));
  if ((tid & 63) == 0) sm[tid >> 6] = m;
  __syncthreads();
  m = fmaxf(fmaxf(sm[0], sm[1]), fmaxf(sm[2], sm[3]));

  float s = 0.f;
  for (int i = start + tid; i < end; i += 256) s += __expf(a[i] - m);
  for (int d = 1; d < 64; d <<= 1) s += __shfl_xor(s, d);
  if ((tid & 63) == 0) sm[4 + (tid >> 6)] = s;
  __syncthreads();
  s = sm[4] + sm[5] + sm[6] + sm[7];

  float rinv = 1.0f / s;
  for (int i = start + tid; i < end; i += 256) w[i] = __expf(a[i] - m) * rinv;
}

// ---------------- kernel 3: z[b] = sum_i w_i * x_i ----------------
__global__ void z_kernel(const float* __restrict__ x, const float* __restrict__ w,
                         const int* __restrict__ batch, float* __restrict__ z) {
  int b = blockIdx.x >> 2, part = blockIdx.x & 3;
  int start = lower_bound(batch, b);
  int end   = lower_bound(batch, b + 1);
  int len = end - start;
  int ps = start + ((len * part) >> 2);
  int pe = start + ((len * (part + 1)) >> 2);
  int col = threadIdx.x << 2;

  f32x4 acc = (f32x4){0.f, 0.f, 0.f, 0.f};
  for (int i = ps; i < pe; ++i) {
    f32x4 xv = *(const f32x4*)(x + ((size_t)i << 10) + col);
    float wi = w[i];
    acc += xv * wi;
  }
  float* zp = z + ((size_t)b << 10) + col;
  atomicAdd(zp + 0, acc[0]);
  atomicAdd(zp + 1, acc[1]);
  atomicAdd(zp + 2, acc[2]);
  atomicAdd(zp + 3, acc[3]);
}

// ---------------- launch ----------------
extern "C" void kernel_launch(void* const* d_in, const int* in_sizes, int n_in,
                              void* d_out, int out_size, void* d_ws, size_t ws_size,
                              hipStream_t stream) {
  const float* x     = (const float*)d_in[0];
  const int*   batch = (const int*)d_in[1];
  const float* W1    = (const float*)d_in[2];
  const float* W2    = (const float*)d_in[3];
  const float* W3    = (const float*)d_in[4];
  float* z = (float*)d_out;

  // ws: [0,2M) wbf ; [2M,3M) a ; [3M,4M) w ; [4M,8M) pm ; [8M,12M) ps ; [12M,16M) pn
  unsigned short* wbf = (unsigned short*)d_ws;
  float* a  = (float*)((char*)d_ws + (2u << 20));
  float* w  = (float*)((char*)d_ws + (3u << 20));
  float* pm = (float*)((char*)d_ws + (4u << 20));
  float* ps = (float*)((char*)d_ws + (8u << 20));
  float* pn = (float*)((char*)d_ws + (12u << 20));

  (void)hipMemsetAsync(d_out, 0, (size_t)N_SEG * D_DIM * sizeof(float), stream);

  cvt_w<<<512, 256, 0, stream>>>(W1, W2, wbf);

  alpha_kernel<<<4096, 512, 0, stream>>>(x, wbf, W3, pm, ps, pn);

  combine_a<<<N_ROWS / 256, 256, 0, stream>>>(pm, ps, pn, a);

  seg_kernel<<<N_SEG, 256, 0, stream>>>(a, batch, w);

  z_kernel<<<N_SEG * 4, 256, 0, stream>>>(x, w, batch, z);
}

// Round 10
// 1248.848 us; speedup vs baseline: 1.4730x; 1.0515x over previous
//
#include <hip/hip_runtime.h>
#include <stdint.h>

#define N_ROWS 262144
#define D_DIM  1024
#define H_DIM  512
#define N_SEG  512

typedef __attribute__((ext_vector_type(4)))  float  f32x4;
typedef __attribute__((ext_vector_type(8)))  __bf16 bf16x8;
typedef __attribute__((ext_vector_type(8)))  unsigned short u16x8;

static __device__ __forceinline__ unsigned short c2bf(float f) {
  union { __bf16 b; unsigned short u; } c; c.b = (__bf16)f; return c.u;   // RNE, pairs fuse to cvt_pk
}
static __device__ __forceinline__ float fast_tanh(float u) {
  return 1.0f - 2.0f / (__expf(2.0f * u) + 1.0f);
}

// ---------------- kernel 0: W1,W2 f32 -> bf16 LDS-image, u/v interleaved ----
// Image for (hs, kt): 16 KB = 16 subtiles (cfi) of 1 KB; subtile = lane l slot
// of 16 B: col c = cfi*16 + (l&15); mat = c&1 (0=W1,1=W2), h = hs*128 + (c>>1);
// k = kt*32 + (l>>4)*8 + e.  elem idx = (hs*32+kt)*8192 + cfi*512 + l*8 + e.
__global__ void cvt_w(const float* __restrict__ W1, const float* __restrict__ W2,
                      unsigned short* __restrict__ wbf) {
  int gid = blockIdx.x * 256 + threadIdx.x;      // 131072
  int l   = gid & 63;
  int cfi = (gid >> 6) & 15;
  int kt  = (gid >> 10) & 31;
  int hs  = gid >> 15;
  int c   = (cfi << 4) + (l & 15);
  int h   = (hs << 7) + (c >> 1);
  int k0  = (kt << 5) + ((l >> 4) << 3);
  const float* src = ((c & 1) ? W2 : W1) + h * 1024 + k0;
  f32x4 f0 = *(const f32x4*)src;
  f32x4 f1 = *(const f32x4*)(src + 4);
  u16x8 v;
  v[0]=c2bf(f0[0]); v[1]=c2bf(f0[1]); v[2]=c2bf(f0[2]); v[3]=c2bf(f0[3]);
  v[4]=c2bf(f1[0]); v[5]=c2bf(f1[1]); v[6]=c2bf(f1[2]); v[7]=c2bf(f1[3]);
  *(u16x8*)(wbf + (size_t)gid * 8) = v;
}

// ---------------- kernel 1: partial (m,s,n) per (row, h-slice) -------------
// Block = 256 rows x (128 h x {u,v}); 8 waves = 2rg x 4cg; wave = 128r x 64c,
// mfma 16x16x32, acc f32x4[8][4] static. BK=32, 32 phases.
// T3/T4/T14 schedule: B via global_load_lds 1 phase ahead; A global->reg
// 2 phases ahead, packed to LDS AFTER compute; barriers are
// s_waitcnt vmcnt(2)+lgkmcnt(0)+s_barrier (A-loads stay in flight).
// LDS 64KB: A dbuf @0/@16384, B dbuf @32768/@49152; partials alias @0.
#define MF(A, B, C) __builtin_amdgcn_mfma_f32_16x16x32_bf16((A), (B), (C), 0, 0, 0)

#define STAGEB(KT, BOFF) do { \
  __builtin_amdgcn_global_load_lds( \
    (const __attribute__((address_space(1))) void*)(wsrc + ((uint32_t)(KT) << 13)), \
    (__attribute__((address_space(3))) void*)(lds + (BOFF) + (wid << 11)), 16, 0, 0); \
  __builtin_amdgcn_global_load_lds( \
    (const __attribute__((address_space(1))) void*)(wsrc + ((uint32_t)(KT) << 13) + 512), \
    (__attribute__((address_space(3))) void*)(lds + (BOFF) + (wid << 11) + 1024), 16, 0, 0); \
} while (0)

#define ALOADP(KT) do { \
  pA0 = *(const f32x4*)(xsrc0 + ((KT) << 5));     pA1 = *(const f32x4*)(xsrc0 + ((KT) << 5) + 4); \
  pB0 = *(const f32x4*)(xsrc1 + ((KT) << 5));     pB1 = *(const f32x4*)(xsrc1 + ((KT) << 5) + 4); \
} while (0)
#define ALOADQ(KT) do { \
  qA0 = *(const f32x4*)(xsrc0 + ((KT) << 5));     qA1 = *(const f32x4*)(xsrc0 + ((KT) << 5) + 4); \
  qB0 = *(const f32x4*)(xsrc1 + ((KT) << 5));     qB1 = *(const f32x4*)(xsrc1 + ((KT) << 5) + 4); \
} while (0)

#define PACKSET(BOFF, A0, A1, B0, B1) do { \
  u16x8 va, vb; \
  va[0]=c2bf(A0[0]); va[1]=c2bf(A0[1]); va[2]=c2bf(A0[2]); va[3]=c2bf(A0[3]); \
  va[4]=c2bf(A1[0]); va[5]=c2bf(A1[1]); va[6]=c2bf(A1[2]); va[7]=c2bf(A1[3]); \
  vb[0]=c2bf(B0[0]); vb[1]=c2bf(B0[1]); vb[2]=c2bf(B0[2]); vb[3]=c2bf(B0[3]); \
  vb[4]=c2bf(B1[0]); vb[5]=c2bf(B1[1]); vb[6]=c2bf(B1[2]); vb[7]=c2bf(B1[3]); \
  *(u16x8*)(lds + (BOFF) + (tid << 4)) = va; \
  *(u16x8*)(lds + (BOFF) + 8192 + (tid << 4)) = vb; \
} while (0)

#define COMPUTE(PAR) do { \
  bf16x8 bf_[4], af[8]; \
  _Pragma("unroll") \
  for (int fc = 0; fc < 4; ++fc) \
    bf_[fc] = *(const bf16x8*)(lds + 32768 + ((PAR) << 14) + (((cg << 2) + fc) << 10) + (lane << 4)); \
  _Pragma("unroll") \
  for (int fr = 0; fr < 8; ++fr) \
    af[fr] = *(const bf16x8*)(lds + ((PAR) << 14) + (((rg << 3) + fr) << 10) + (lane << 4)); \
  __builtin_amdgcn_s_setprio(1); \
  _Pragma("unroll") \
  for (int fr = 0; fr < 8; ++fr) \
    _Pragma("unroll") \
    for (int fc = 0; fc < 4; ++fc) \
      acc[fr][fc] = MF(af[fr], bf_[fc], acc[fr][fc]); \
  __builtin_amdgcn_s_setprio(0); \
} while (0)

#define BAR2() do { \
  asm volatile("s_waitcnt vmcnt(2) lgkmcnt(0)" ::: "memory"); \
  __builtin_amdgcn_s_barrier(); \
} while (0)
#define BAR0() do { \
  asm volatile("s_waitcnt vmcnt(0) lgkmcnt(0)" ::: "memory"); \
  __builtin_amdgcn_s_barrier(); \
} while (0)

__launch_bounds__(512, 2)
__global__ void alpha_kernel(const float* __restrict__ x,
                             const unsigned short* __restrict__ wbf,
                             const float* __restrict__ W3,
                             float* __restrict__ pm, float* __restrict__ ps,
                             float* __restrict__ pn)
{
  __shared__ unsigned char lds[65536];
  const int tid  = threadIdx.x;
  const int lane = tid & 63;
  const int wid  = tid >> 6;                     // 0..7
  const int rg   = wid >> 2;                     // 0..1  row half (128 rows)
  const int cg   = wid & 3;                      // 0..3  col quarter (64 vcols = 32 h)
  const int l15  = lane & 15;
  const int lg   = lane >> 4;                    // 0..3
  const int bid  = blockIdx.x;
  const int rt   = ((bid >> 5) << 3) + (bid & 7);   // rowtile (same XCD for all hs)
  const int hs   = (bid >> 3) & 3;                  // h-slice 0..3
  const int row0 = rt << 8;

  // A staging: thread t -> slots t and t+512; slot s: row = (s>>6)*16 + (s&15),
  // k = kt*32 + ((s>>4)&3)*8 + [0,8)
  const int s0r = ((tid >> 6) << 4) + (tid & 15);
  const int s0k = ((tid >> 4) & 3) << 3;
  const float* xsrc0 = x + (size_t)(row0 + s0r) * 1024 + s0k;
  const float* xsrc1 = xsrc0 + (size_t)128 * 1024;

  // B staging source (per-lane)
  const unsigned short* wsrc = wbf + ((uint32_t)hs << 18) + ((uint32_t)wid << 10) + ((uint32_t)lane << 3);

  f32x4 acc[8][4];
  #pragma unroll
  for (int fr = 0; fr < 8; ++fr)
    #pragma unroll
    for (int fc = 0; fc < 4; ++fc) acc[fr][fc] = (f32x4){0.f, 0.f, 0.f, 0.f};

  f32x4 pA0, pA1, pB0, pB1;                      // A-set parity 0
  f32x4 qA0, qA1, qB0, qB1;                      // A-set parity 1

  // ---- prologue ----
  STAGEB(0, 32768);                              // B(0) -> Bbuf0
  ALOADP(0);                                     // A(0) -> set p
  ALOADQ(1);                                     // A(1) -> set q
  PACKSET(0, pA0, pA1, pB0, pB1);                // A(0) -> Abuf0 (auto vmcnt)
  BAR2();                                        // leave A(1) in flight

  // ---- 30 steady phases (A 2-deep, B 1-deep, counted vmcnt) ----
  #pragma unroll 1
  for (int kt = 0; kt < 30; kt += 2) {
    // even phase kt
    STAGEB(kt + 1, 49152);                       // B(kt+1) -> Bbuf1
    ALOADP(kt + 2);                              // A(kt+2) -> set p
    COMPUTE(0);                                  // Abuf0 x Bbuf0
    PACKSET(16384, qA0, qA1, qB0, qB1);          // A(kt+1) -> Abuf1 (write-late)
    BAR2();
    // odd phase kt+1
    STAGEB(kt + 2, 32768);                       // B(kt+2) -> Bbuf0
    ALOADQ(kt + 3);                              // A(kt+3) -> set q
    COMPUTE(1);                                  // Abuf1 x Bbuf1
    PACKSET(0, pA0, pA1, pB0, pB1);              // A(kt+2) -> Abuf0
    BAR2();
  }

  // ---- phase 30 ----
  STAGEB(31, 49152);                             // B(31) -> Bbuf1
  COMPUTE(0);
  PACKSET(16384, qA0, qA1, qB0, qB1);            // A(31) -> Abuf1
  BAR0();
  // ---- phase 31 ----
  COMPUTE(1);

  // ---- epilogue: fully static, in-register via shfl ----
  // C/D map (m89): col = lane&15, row = lg*4 + j. Lane's col c = cg*64+fc*16+l15;
  // parity(c) = parity(lane): even lane = u[h], odd lane = v-logit[h],
  // h = hs*128 + (c>>1); shfl_xor(1) moves the gate across.
  float w3v[4];
  #pragma unroll
  for (int fc = 0; fc < 4; ++fc)
    w3v[fc] = W3[(hs << 7) + (((cg << 6) + (fc << 4) + l15) >> 1)];

  float* pmb = (float*)(lds);                    // [4 cg][256 rows], aliases Abuf0
  float* psb = pmb + 1024;
  float* pnb = psb + 1024;

  #pragma unroll
  for (int fr = 0; fr < 8; ++fr) {
    f32x4 mv, sv, nv;
    #pragma unroll
    for (int j = 0; j < 4; ++j) {
      float g0 = fast_tanh(acc[fr][0][j]) * w3v[0];
      float g1 = fast_tanh(acc[fr][1][j]) * w3v[1];
      float g2 = fast_tanh(acc[fr][2][j]) * w3v[2];
      float g3 = fast_tanh(acc[fr][3][j]) * w3v[3];
      float gs0 = __shfl_xor(g0, 1);
      float gs1 = __shfl_xor(g1, 1);
      float gs2 = __shfl_xor(g2, 1);
      float gs3 = __shfl_xor(g3, 1);
      float mj = fmaxf(fmaxf(acc[fr][0][j], acc[fr][1][j]),
                       fmaxf(acc[fr][2][j], acc[fr][3][j]));
      mj = fmaxf(mj, __shfl_xor(mj, 2));
      mj = fmaxf(mj, __shfl_xor(mj, 4));
      mj = fmaxf(mj, __shfl_xor(mj, 8));
      float p0 = __expf(acc[fr][0][j] - mj);
      float p1 = __expf(acc[fr][1][j] - mj);
      float p2 = __expf(acc[fr][2][j] - mj);
      float p3 = __expf(acc[fr][3][j] - mj);
      float sj = p0 + p1 + p2 + p3;
      float nj = gs0 * p0 + gs1 * p1 + gs2 * p2 + gs3 * p3;
      sj += __shfl_xor(sj, 2); nj += __shfl_xor(nj, 2);
      sj += __shfl_xor(sj, 4); nj += __shfl_xor(nj, 4);
      sj += __shfl_xor(sj, 8); nj += __shfl_xor(nj, 8);
      mv[j] = mj; sv[j] = sj; nv[j] = nj;
    }
    if (l15 == 1) {                              // lanes 1,17,33,49 (one per lg)
      int idx = (cg << 8) + (rg << 7) + (fr << 4) + (lg << 2);
      *(f32x4*)&pmb[idx] = mv;
      *(f32x4*)&psb[idx] = sv;
      *(f32x4*)&pnb[idx] = nv;
    }
  }
  __syncthreads();
  if (tid < 256) {
    float m0 = pmb[tid], m1 = pmb[256 + tid], m2 = pmb[512 + tid], m3 = pmb[768 + tid];
    float M = fmaxf(fmaxf(m0, m1), fmaxf(m2, m3));
    float e0 = __expf(m0 - M), e1 = __expf(m1 - M), e2 = __expf(m2 - M), e3 = __expf(m3 - M);
    float S  = psb[tid]*e0 + psb[256+tid]*e1 + psb[512+tid]*e2 + psb[768+tid]*e3;
    float Nn = pnb[tid]*e0 + pnb[256+tid]*e1 + pnb[512+tid]*e2 + pnb[768+tid]*e3;
    size_t r = (size_t)(row0 + tid);
    pm[r * 4 + hs] = M;
    ps[r * 4 + hs] = S;
    pn[r * 4 + hs] = Nn;
  }
}

// ---------------- kernel 1b: combine h-slice partials -> a[i] --------------
__global__ void combine_a(const float* __restrict__ pm, const float* __restrict__ ps,
                          const float* __restrict__ pn, float* __restrict__ a) {
  size_t r = (size_t)blockIdx.x * 256 + threadIdx.x;
  float M = -3.4e38f;
  #pragma unroll
  for (int s = 0; s < 4; ++s) M = fmaxf(M, pm[r * 4 + s]);
  float S = 0.f, Nn = 0.f;
  #pragma unroll
  for (int s = 0; s < 4; ++s) {
    float e = __expf(pm[r * 4 + s] - M);
    S  += ps[r * 4 + s] * e;
    Nn += pn[r * 4 + s] * e;
  }
  a[r] = Nn / S;
}

// ---------------- kernel 2: segment softmax weights ----------------
static __device__ __forceinline__ int lower_bound(const int* __restrict__ batch, int key) {
  int lo = 0, hi = N_ROWS;
  while (lo < hi) { int mid = (lo + hi) >> 1; if (batch[mid] < key) lo = mid + 1; else hi = mid; }
  return lo;
}

__global__ void seg_kernel(const float* __restrict__ a, const int* __restrict__ batch,
                           float* __restrict__ w) {
  __shared__ float sm[8];
  int b = blockIdx.x;
  int start = lower_bound(batch, b);
  int end   = lower_bound(batch, b + 1);
  int tid = threadIdx.x;

  float m = -3.4e38f;
  for (int i = start + tid; i < end; i += 256) m = fmaxf(m, a[i]);
  for (int d = 1; d < 64; d <<= 1) m = fmaxf(m, __shfl_xor(m, d));
  if ((tid & 63) == 0) sm[tid >> 6] = m;
  __syncthreads();
  m = fmaxf(fmaxf(sm[0], sm[1]), fmaxf(sm[2], sm[3]));

  float s = 0.f;
  for (int i = start + tid; i < end; i += 256) s += __expf(a[i] - m);
  for (int d = 1; d < 64; d <<= 1) s += __shfl_xor(s, d);
  if ((tid & 63) == 0) sm[4 + (tid >> 6)] = s;
  __syncthreads();
  s = sm[4] + sm[5] + sm[6] + sm[7];

  float rinv = 1.0f / s;
  for (int i = start + tid; i < end; i += 256) w[i] = __expf(a[i] - m) * rinv;
}

// ---------------- kernel 3: z[b] = sum_i w_i * x_i ----------------
__global__ void z_kernel(const float* __restrict__ x, const float* __restrict__ w,
                         const int* __restrict__ batch, float* __restrict__ z) {
  int b = blockIdx.x >> 2, part = blockIdx.x & 3;
  int start = lower_bound(batch, b);
  int end   = lower_bound(batch, b + 1);
  int len = end - start;
  int ps = start + ((len * part) >> 2);
  int pe = start + ((len * (part + 1)) >> 2);
  int col = threadIdx.x << 2;

  f32x4 acc = (f32x4){0.f, 0.f, 0.f, 0.f};
  for (int i = ps; i < pe; ++i) {
    f32x4 xv = *(const f32x4*)(x + ((size_t)i << 10) + col);
    float wi = w[i];
    acc += xv * wi;
  }
  float* zp = z + ((size_t)b << 10) + col;
  atomicAdd(zp + 0, acc[0]);
  atomicAdd(zp + 1, acc[1]);
  atomicAdd(zp + 2, acc[2]);
  atomicAdd(zp + 3, acc[3]);
}

// ---------------- launch ----------------
extern "C" void kernel_launch(void* const* d_in, const int* in_sizes, int n_in,
                              void* d_out, int out_size, void* d_ws, size_t ws_size,
                              hipStream_t stream) {
  const float* x     = (const float*)d_in[0];
  const int*   batch = (const int*)d_in[1];
  const float* W1    = (const float*)d_in[2];
  const float* W2    = (const float*)d_in[3];
  const float* W3    = (const float*)d_in[4];
  float* z = (float*)d_out;

  // ws: [0,2M) wbf ; [2M,3M) a ; [3M,4M) w ; [4M,8M) pm ; [8M,12M) ps ; [12M,16M) pn
  unsigned short* wbf = (unsigned short*)d_ws;
  float* a  = (float*)((char*)d_ws + (2u << 20));
  float* w  = (float*)((char*)d_ws + (3u << 20));
  float* pm = (float*)((char*)d_ws + (4u << 20));
  float* ps = (float*)((char*)d_ws + (8u << 20));
  float* pn = (float*)((char*)d_ws + (12u << 20));

  (void)hipMemsetAsync(d_out, 0, (size_t)N_SEG * D_DIM * sizeof(float), stream);

  cvt_w<<<512, 256, 0, stream>>>(W1, W2, wbf);

  alpha_kernel<<<4096, 512, 0, stream>>>(x, wbf, W3, pm, ps, pn);

  combine_a<<<N_ROWS / 256, 256, 0, stream>>>(pm, ps, pn, a);

  seg_kernel<<<N_SEG, 256, 0, stream>>>(a, batch, w);

  z_kernel<<<N_SEG * 4, 256, 0, stream>>>(x, w, batch, z);
}

// Round 11
// 1034.944 us; speedup vs baseline: 1.7775x; 1.2067x over previous
//
#include <hip/hip_runtime.h>
#include <stdint.h>

#define N_ROWS 262144
#define D_DIM  1024
#define H_DIM  512
#define N_SEG  512

typedef __attribute__((ext_vector_type(4)))  float  f32x4;
typedef __attribute__((ext_vector_type(8)))  __bf16 bf16x8;
typedef __attribute__((ext_vector_type(8)))  unsigned short u16x8;

static __device__ __forceinline__ unsigned short c2bf(float f) {
  union { __bf16 b; unsigned short u; } c; c.b = (__bf16)f; return c.u;   // RNE, pairs fuse to cvt_pk
}
static __device__ __forceinline__ float fast_tanh(float u) {
  return 1.0f - 2.0f / (__expf(2.0f * u) + 1.0f);
}

// ---------------- kernel 0: W1,W2 f32 -> bf16 LDS-image, u/v interleaved ----
// Image for (hs, kt): 16 KB = 16 subtiles (cfi) of 1 KB; subtile = lane l slot
// of 16 B: col c = cfi*16 + (l&15); mat = c&1 (0=W1,1=W2), h = hs*128 + (c>>1);
// k = kt*32 + (l>>4)*8 + e.  elem idx = (hs*32+kt)*8192 + cfi*512 + l*8 + e.
__global__ void cvt_w(const float* __restrict__ W1, const float* __restrict__ W2,
                      unsigned short* __restrict__ wbf) {
  int gid = blockIdx.x * 256 + threadIdx.x;      // 131072
  int l   = gid & 63;
  int cfi = (gid >> 6) & 15;
  int kt  = (gid >> 10) & 31;
  int hs  = gid >> 15;
  int c   = (cfi << 4) + (l & 15);
  int h   = (hs << 7) + (c >> 1);
  int k0  = (kt << 5) + ((l >> 4) << 3);
  const float* src = ((c & 1) ? W2 : W1) + h * 1024 + k0;
  f32x4 f0 = *(const f32x4*)src;
  f32x4 f1 = *(const f32x4*)(src + 4);
  u16x8 v;
  v[0]=c2bf(f0[0]); v[1]=c2bf(f0[1]); v[2]=c2bf(f0[2]); v[3]=c2bf(f0[3]);
  v[4]=c2bf(f1[0]); v[5]=c2bf(f1[1]); v[6]=c2bf(f1[2]); v[7]=c2bf(f1[3]);
  *(u16x8*)(wbf + (size_t)gid * 8) = v;
}

// ---------------- kernel 1: partial (m,s,n) per (row, h-slice) -------------
// Block = 128 rows x (128 h x {u,v}); 512 thr, 8 waves = 2rg x 4cg;
// wave = 64r x 64c via mfma 16x16x32, acc f32x4[4][4] (static) = 64 regs ->
// <=128 total -> 2 blocks/CU, 4 waves/SIMD (the occupancy R7 showed matters).
// B via global_load_lds from image 1 phase ahead; A f32->reg->pack-late;
// barrier = s_waitcnt vmcnt(2)+lgkmcnt(0)+s_barrier (A-loads span barriers).
// LDS 48KB: A dbuf @0/@8192 (8KB), B dbuf @16384/@32768 (16KB); partials @0.
#define MF(A, B, C) __builtin_amdgcn_mfma_f32_16x16x32_bf16((A), (B), (C), 0, 0, 0)

#define STAGEB(KT, BOFF) do { \
  __builtin_amdgcn_global_load_lds( \
    (const __attribute__((address_space(1))) void*)(wsrc + ((uint32_t)(KT) << 13)), \
    (__attribute__((address_space(3))) void*)(lds + (BOFF) + (wid << 11)), 16, 0, 0); \
  __builtin_amdgcn_global_load_lds( \
    (const __attribute__((address_space(1))) void*)(wsrc + ((uint32_t)(KT) << 13) + 512), \
    (__attribute__((address_space(3))) void*)(lds + (BOFF) + (wid << 11) + 1024), 16, 0, 0); \
} while (0)

#define ALOAD(KT) do { \
  rA0 = *(const f32x4*)(xsrc + ((KT) << 5)); \
  rA1 = *(const f32x4*)(xsrc + ((KT) << 5) + 4); \
} while (0)

#define PACKA(BOFF) do { \
  u16x8 va; \
  va[0]=c2bf(rA0[0]); va[1]=c2bf(rA0[1]); va[2]=c2bf(rA0[2]); va[3]=c2bf(rA0[3]); \
  va[4]=c2bf(rA1[0]); va[5]=c2bf(rA1[1]); va[6]=c2bf(rA1[2]); va[7]=c2bf(rA1[3]); \
  *(u16x8*)(lds + (BOFF) + (tid << 4)) = va; \
} while (0)

#define COMPUTE(ABUF, BBUF) do { \
  bf16x8 bf_[4], af[4]; \
  _Pragma("unroll") \
  for (int fc = 0; fc < 4; ++fc) \
    bf_[fc] = *(const bf16x8*)(lds + (BBUF) + (((cg << 2) + fc) << 10) + (lane << 4)); \
  _Pragma("unroll") \
  for (int fr = 0; fr < 4; ++fr) \
    af[fr] = *(const bf16x8*)(lds + (ABUF) + (((rg << 2) + fr) << 10) + (lane << 4)); \
  __builtin_amdgcn_s_setprio(1); \
  _Pragma("unroll") \
  for (int fr = 0; fr < 4; ++fr) \
    _Pragma("unroll") \
    for (int fc = 0; fc < 4; ++fc) \
      acc[fr][fc] = MF(af[fr], bf_[fc], acc[fr][fc]); \
  __builtin_amdgcn_s_setprio(0); \
} while (0)

#define BAR2() do { \
  asm volatile("s_waitcnt vmcnt(2) lgkmcnt(0)" ::: "memory"); \
  __builtin_amdgcn_s_barrier(); \
} while (0)
#define BAR0() do { \
  asm volatile("s_waitcnt vmcnt(0) lgkmcnt(0)" ::: "memory"); \
  __builtin_amdgcn_s_barrier(); \
} while (0)

__launch_bounds__(512, 4)
__global__ void alpha_kernel(const float* __restrict__ x,
                             const unsigned short* __restrict__ wbf,
                             const float* __restrict__ W3,
                             float* __restrict__ pm, float* __restrict__ ps,
                             float* __restrict__ pn)
{
  __shared__ unsigned char lds[49152];
  const int tid  = threadIdx.x;
  const int lane = tid & 63;
  const int wid  = tid >> 6;                     // 0..7
  const int rg   = wid >> 2;                     // 0..1  row half (64 rows)
  const int cg   = wid & 3;                      // 0..3  col quarter (64 vcols = 32 h)
  const int l15  = lane & 15;
  const int lg   = lane >> 4;                    // 0..3
  const int bid  = blockIdx.x;
  const int rt   = ((bid >> 5) << 3) + (bid & 7);   // rowtile 0..2047 (hs-group same XCD)
  const int hs   = (bid >> 3) & 3;                  // h-slice 0..3
  const int row0 = rt << 7;                         // 128 rows/block

  // A staging: thread t -> slot t (16B bf16): row = (t>>6)*16 + (t&15),
  // k = kt*32 + ((t>>4)&3)*8 + [0,8)
  const float* xsrc = x + (size_t)(row0 + ((tid >> 6) << 4) + (tid & 15)) * 1024
                        + (((tid >> 4) & 3) << 3);

  // B staging source (per-lane), image from cvt_w
  const unsigned short* wsrc = wbf + ((uint32_t)hs << 18) + ((uint32_t)wid << 10) + ((uint32_t)lane << 3);

  f32x4 acc[4][4];
  #pragma unroll
  for (int fr = 0; fr < 4; ++fr)
    #pragma unroll
    for (int fc = 0; fc < 4; ++fc) acc[fr][fc] = (f32x4){0.f, 0.f, 0.f, 0.f};

  f32x4 rA0, rA1;

  // ---- prologue ----
  STAGEB(0, 16384);                              // B(0) -> B0
  ALOAD(0);
  PACKA(0);                                      // A(0) -> A0 (waits own loads)
  ALOAD(1);                                      // stays in flight across barrier
  BAR2();                                        // drains STAGEB(0), keeps ALOAD(1)

  // ---- 30 phases in pairs + 2 tail phases ----
  #pragma unroll 1
  for (int kt = 0; kt < 30; kt += 2) {
    // phase kt (even): A0 x B0
    STAGEB(kt + 1, 32768);                       // B(kt+1) -> B1
    COMPUTE(0, 16384);
    PACKA(8192);                                 // A(kt+1) -> A1 (regs 1 phase old)
    ALOAD(kt + 2);
    BAR2();                                      // drains STAGEB(kt+1), keeps ALOAD
    // phase kt+1 (odd): A1 x B1
    STAGEB(kt + 2, 16384);                       // B(kt+2) -> B0
    COMPUTE(8192, 32768);
    PACKA(0);                                    // A(kt+2) -> A0
    ALOAD(kt + 3);
    BAR2();
  }
  // phase 30: A0 x B0; stage B(31); pack A(31)
  STAGEB(31, 32768);
  COMPUTE(0, 16384);
  PACKA(8192);
  BAR0();                                        // only STAGEB(31) in flight -> drain
  // phase 31: A1 x B1
  COMPUTE(8192, 32768);

  // ---- epilogue: fully static, in-register via shfl ----
  // C/D map (m89): col = lane&15, row = lg*4 + j. Lane's col c = cg*64+fc*16+l15;
  // parity(c) = parity(lane): even lane = u[h], odd lane = v-logit[h],
  // h = hs*128 + (c>>1); shfl_xor(1) moves the gate across.
  float w3v[4];
  #pragma unroll
  for (int fc = 0; fc < 4; ++fc)
    w3v[fc] = W3[(hs << 7) + (((cg << 6) + (fc << 4) + l15) >> 1)];

  float* pmb = (float*)(lds);                    // [4 cg][128 rows], aliases A0
  float* psb = pmb + 512;
  float* pnb = psb + 512;

  #pragma unroll
  for (int fr = 0; fr < 4; ++fr) {
    f32x4 mv, sv, nv;
    #pragma unroll
    for (int j = 0; j < 4; ++j) {
      float g0 = fast_tanh(acc[fr][0][j]) * w3v[0];
      float g1 = fast_tanh(acc[fr][1][j]) * w3v[1];
      float g2 = fast_tanh(acc[fr][2][j]) * w3v[2];
      float g3 = fast_tanh(acc[fr][3][j]) * w3v[3];
      float gs0 = __shfl_xor(g0, 1);
      float gs1 = __shfl_xor(g1, 1);
      float gs2 = __shfl_xor(g2, 1);
      float gs3 = __shfl_xor(g3, 1);
      float mj = fmaxf(fmaxf(acc[fr][0][j], acc[fr][1][j]),
                       fmaxf(acc[fr][2][j], acc[fr][3][j]));
      mj = fmaxf(mj, __shfl_xor(mj, 2));
      mj = fmaxf(mj, __shfl_xor(mj, 4));
      mj = fmaxf(mj, __shfl_xor(mj, 8));
      float p0 = __expf(acc[fr][0][j] - mj);
      float p1 = __expf(acc[fr][1][j] - mj);
      float p2 = __expf(acc[fr][2][j] - mj);
      float p3 = __expf(acc[fr][3][j] - mj);
      float sj = p0 + p1 + p2 + p3;
      float nj = gs0 * p0 + gs1 * p1 + gs2 * p2 + gs3 * p3;
      sj += __shfl_xor(sj, 2); nj += __shfl_xor(nj, 2);
      sj += __shfl_xor(sj, 4); nj += __shfl_xor(nj, 4);
      sj += __shfl_xor(sj, 8); nj += __shfl_xor(nj, 8);
      mv[j] = mj; sv[j] = sj; nv[j] = nj;
    }
    if (l15 == 1) {                              // lanes 1,17,33,49 (one per lg)
      int idx = (cg << 7) + (rg << 6) + (fr << 4) + (lg << 2);
      *(f32x4*)&pmb[idx] = mv;
      *(f32x4*)&psb[idx] = sv;
      *(f32x4*)&pnb[idx] = nv;
    }
  }
  __syncthreads();
  if (tid < 128) {
    float m0 = pmb[tid], m1 = pmb[128 + tid], m2 = pmb[256 + tid], m3 = pmb[384 + tid];
    float M = fmaxf(fmaxf(m0, m1), fmaxf(m2, m3));
    float e0 = __expf(m0 - M), e1 = __expf(m1 - M), e2 = __expf(m2 - M), e3 = __expf(m3 - M);
    float S  = psb[tid]*e0 + psb[128+tid]*e1 + psb[256+tid]*e2 + psb[384+tid]*e3;
    float Nn = pnb[tid]*e0 + pnb[128+tid]*e1 + pnb[256+tid]*e2 + pnb[384+tid]*e3;
    size_t r = (size_t)(row0 + tid);
    pm[r * 4 + hs] = M;
    ps[r * 4 + hs] = S;
    pn[r * 4 + hs] = Nn;
  }
}

// ---------------- kernel 1b: combine h-slice partials -> a[i] --------------
__global__ void combine_a(const float* __restrict__ pm, const float* __restrict__ ps,
                          const float* __restrict__ pn, float* __restrict__ a) {
  size_t r = (size_t)blockIdx.x * 256 + threadIdx.x;
  float M = -3.4e38f;
  #pragma unroll
  for (int s = 0; s < 4; ++s) M = fmaxf(M, pm[r * 4 + s]);
  float S = 0.f, Nn = 0.f;
  #pragma unroll
  for (int s = 0; s < 4; ++s) {
    float e = __expf(pm[r * 4 + s] - M);
    S  += ps[r * 4 + s] * e;
    Nn += pn[r * 4 + s] * e;
  }
  a[r] = Nn / S;
}

// ---------------- kernel 2: segment softmax weights ----------------
static __device__ __forceinline__ int lower_bound(const int* __restrict__ batch, int key) {
  int lo = 0, hi = N_ROWS;
  while (lo < hi) { int mid = (lo + hi) >> 1; if (batch[mid] < key) lo = mid + 1; else hi = mid; }
  return lo;
}

__global__ void seg_kernel(const float* __restrict__ a, const int* __restrict__ batch,
                           float* __restrict__ w) {
  __shared__ float sm[8];
  int b = blockIdx.x;
  int start = lower_bound(batch, b);
  int end   = lower_bound(batch, b + 1);
  int tid = threadIdx.x;

  float m = -3.4e38f;
  for (int i = start + tid; i < end; i += 256) m = fmaxf(m, a[i]);
  for (int d = 1; d < 64; d <<= 1) m = fmaxf(m, __shfl_xor(m, d));
  if ((tid & 63) == 0) sm[tid >> 6] = m;
  __syncthreads();
  m = fmaxf(fmaxf(sm[0], sm[1]), fmaxf(sm[2], sm[3]));

  float s = 0.f;
  for (int i = start + tid; i < end; i += 256) s += __expf(a[i] - m);
  for (int d = 1; d < 64; d <<= 1) s += __shfl_xor(s, d);
  if ((tid & 63) == 0) sm[4 + (tid >> 6)] = s;
  __syncthreads();
  s = sm[4] + sm[5] + sm[6] + sm[7];

  float rinv = 1.0f / s;
  for (int i = start + tid; i < end; i += 256) w[i] = __expf(a[i] - m) * rinv;
}

// ---------------- kernel 3: z[b] = sum_i w_i * x_i ----------------
__global__ void z_kernel(const float* __restrict__ x, const float* __restrict__ w,
                         const int* __restrict__ batch, float* __restrict__ z) {
  int b = blockIdx.x >> 2, part = blockIdx.x & 3;
  int start = lower_bound(batch, b);
  int end   = lower_bound(batch, b + 1);
  int len = end - start;
  int ps = start + ((len * part) >> 2);
  int pe = start + ((len * (part + 1)) >> 2);
  int col = threadIdx.x << 2;

  f32x4 acc = (f32x4){0.f, 0.f, 0.f, 0.f};
  for (int i = ps; i < pe; ++i) {
    f32x4 xv = *(const f32x4*)(x + ((size_t)i << 10) + col);
    float wi = w[i];
    acc += xv * wi;
  }
  float* zp = z + ((size_t)b << 10) + col;
  atomicAdd(zp + 0, acc[0]);
  atomicAdd(zp + 1, acc[1]);
  atomicAdd(zp + 2, acc[2]);
  atomicAdd(zp + 3, acc[3]);
}

// ---------------- launch ----------------
extern "C" void kernel_launch(void* const* d_in, const int* in_sizes, int n_in,
                              void* d_out, int out_size, void* d_ws, size_t ws_size,
                              hipStream_t stream) {
  const float* x     = (const float*)d_in[0];
  const int*   batch = (const int*)d_in[1];
  const float* W1    = (const float*)d_in[2];
  const float* W2    = (const float*)d_in[3];
  const float* W3    = (const float*)d_in[4];
  float* z = (float*)d_out;

  // ws: [0,2M) wbf ; [2M,3M) a ; [3M,4M) w ; [4M,8M) pm ; [8M,12M) ps ; [12M,16M) pn
  unsigned short* wbf = (unsigned short*)d_ws;
  float* a  = (float*)((char*)d_ws + (2u << 20));
  float* w  = (float*)((char*)d_ws + (3u << 20));
  float* pm = (float*)((char*)d_ws + (4u << 20));
  float* ps = (float*)((char*)d_ws + (8u << 20));
  float* pn = (float*)((char*)d_ws + (12u << 20));

  (void)hipMemsetAsync(d_out, 0, (size_t)N_SEG * D_DIM * sizeof(float), stream);

  cvt_w<<<512, 256, 0, stream>>>(W1, W2, wbf);

  alpha_kernel<<<8192, 512, 0, stream>>>(x, wbf, W3, pm, ps, pn);

  combine_a<<<N_ROWS / 256, 256, 0, stream>>>(pm, ps, pn, a);

  seg_kernel<<<N_SEG, 256, 0, stream>>>(a, batch, w);

  z_kernel<<<N_SEG * 4, 256, 0, stream>>>(x, w, batch, z);
}